// Round 2
// baseline (122.898 us; speedup 1.0000x reference)
//
#include <hip/hip_runtime.h>

// Problem constants: IMG=512, CUT_SIZE=224, CUTN=64, B=4, C=3
constexpr int S  = 224;
constexpr int B  = 4;
constexpr int C  = 3;
constexpr int H  = 512;
constexpr int W  = 512;
constexpr int N  = 64;
constexpr int PLANES = B * C;              // 12
constexpr int JV     = S / 4;              // 56 float4 per row
constexpr int HROWS  = S / 2;              // 112 rows per half-plane
constexpr int F_HP   = N * HROWS * JV;     // 401,408 float4 per half-plane (all n)
constexpr int NXCD   = 8;
constexpr int PER_XCD = 3 * F_HP;          // 24 half-planes / 8 XCDs = 3 each
constexpr int ITER   = 4;
constexpr int BLOCK  = 256;
constexpr int BLOCKS_PER_XCD = PER_XCD / (ITER * BLOCK);   // 1176 (exact)
constexpr int GRID   = NXCD * BLOCKS_PER_XCD;              // 9408

__global__ __launch_bounds__(256) void cutouts_kernel(
    const float* __restrict__ x,
    const int*   __restrict__ sizes,
    const int*   __restrict__ offx,
    const int*   __restrict__ offy,
    float*       __restrict__ out)
{
    const int k   = blockIdx.x & (NXCD - 1);   // XCD id (round-robin dispatch heuristic)
    const int blk = blockIdx.x >> 3;
    const int base = blk * (ITER * BLOCK);

    #pragma unroll
    for (int t = 0; t < ITER; ++t) {
        const int w = base + t * BLOCK + threadIdx.x;     // [0, PER_XCD)

        // which of this XCD's 3 half-planes
        const int hpsel = (w >= 2 * F_HP) ? 2 : (w >= F_HP ? 1 : 0);
        const int rem   = w - hpsel * F_HP;
        const int hp    = k + (hpsel << 3);               // 0..23
        const int pi    = hp >> 1;                        // plane = b*C+c, 0..11
        const int hh    = hp & 1;                         // top/bottom half

        const int n   = rem / (HROWS * JV);               // cutout index
        const int r2  = rem - n * (HROWS * JV);
        const int il  = r2 / JV;
        const int jv  = r2 - il * JV;
        const int i   = hh * HROWS + il;                  // output row
        const int j   = jv * 4;                           // output col (x4)

        const int   sz    = sizes[n];
        const float scale = (float)sz * (1.0f / (float)S);

        // vertical interp (frac BEFORE clamp, matching reference)
        const float sy  = fmaxf(scale * ((float)i + 0.5f) - 0.5f, 0.0f);
        const float fiy = floorf(sy);
        const float fy  = sy - fiy;
        const int   iy0 = min((int)fiy, sz - 1);
        const int   iy1 = min(iy0 + 1, sz - 1);

        const float* baseplane = x + (size_t)pi * (H * W);
        const float* row0 = baseplane + (size_t)(offy[n] + iy0) * W;
        const float* row1 = baseplane + (size_t)(offy[n] + iy1) * W;
        const int    ox   = offx[n];

        float4 res;
        float* rp = reinterpret_cast<float*>(&res);
        #pragma unroll
        for (int kk = 0; kk < 4; ++kk) {
            const float sx  = fmaxf(scale * ((float)(j + kk) + 0.5f) - 0.5f, 0.0f);
            const float fix = floorf(sx);
            const float fx  = sx - fix;
            const int   ix0 = min((int)fix, sz - 1);
            const int   ix1 = min(ix0 + 1, sz - 1);

            const float v00 = row0[ox + ix0];
            const float v01 = row0[ox + ix1];
            const float v10 = row1[ox + ix0];
            const float v11 = row1[ox + ix1];

            const float top = v00 + (v01 - v00) * fx;
            const float bot = v10 + (v11 - v10) * fx;
            rp[kk] = top + (bot - top) * fy;
        }

        // out[((n*B+b)*C+c)]·S·S + i·S + j  with (b*C+c)==pi
        float* outp = out + (size_t)(n * PLANES + pi) * (S * S) + i * S + j;
        *reinterpret_cast<float4*>(outp) = res;
    }
}

extern "C" void kernel_launch(void* const* d_in, const int* in_sizes, int n_in,
                              void* d_out, int out_size, void* d_ws, size_t ws_size,
                              hipStream_t stream) {
    const float* x     = (const float*)d_in[0];
    const int*   sizes = (const int*)d_in[1];
    const int*   offx  = (const int*)d_in[2];
    const int*   offy  = (const int*)d_in[3];
    float* out = (float*)d_out;

    cutouts_kernel<<<GRID, BLOCK, 0, stream>>>(x, sizes, offx, offy, out);
}

// Round 3
// 47.495 us; speedup vs baseline: 2.5876x; 2.5876x over previous
//
#include <hip/hip_runtime.h>

// Problem constants: IMG=512, CUT_SIZE=224, CUTN=64, B=4, C=3
constexpr int S  = 224;
constexpr int B  = 4;
constexpr int C  = 3;
constexpr int H  = 512;
constexpr int W  = 512;
constexpr int N  = 64;
constexpr int PLANES = B * C;                    // 12
constexpr int HROWS  = S / 2;                    // 112 rows per half-plane
constexpr int ROWS_PER_HP  = N * HROWS;          // 7168 (one half-plane, all cutouts)
constexpr int ROWS_PER_XCD = 3 * ROWS_PER_HP;    // 21504 (24 half-planes / 8 XCDs)
constexpr int WPB    = 4;                        // waves per block, 1 output row each
constexpr int BLOCKS_PER_XCD = ROWS_PER_XCD / WPB;  // 5376 (exact)
constexpr int GRID   = 8 * BLOCKS_PER_XCD;          // 43008

__device__ __forceinline__ void load_lds16(const float* g, float* l) {
    // width-16 global->LDS DMA: HW writes lds[base + lane*16B] from per-lane g
    __builtin_amdgcn_global_load_lds(
        (const __attribute__((address_space(1))) void*)g,
        (__attribute__((address_space(3))) void*)l,
        16, 0, 0);
}

__global__ __launch_bounds__(256) void cutouts_kernel(
    const float* __restrict__ x,
    const int*   __restrict__ sizes,
    const int*   __restrict__ offx,
    const int*   __restrict__ offy,
    float*       __restrict__ out)
{
    __shared__ float lds[WPB][2][W];             // 16 KiB

    const int lane = threadIdx.x & 63;
    const int wv   = threadIdx.x >> 6;

    // XCD-affine row decomposition (same half-plane ownership as R1)
    const int k     = blockIdx.x & 7;                       // XCD (round-robin heuristic)
    const int w_row = (blockIdx.x >> 3) * WPB + wv;         // [0, 21504)
    const int hpsel = w_row / ROWS_PER_HP;                  // 0..2
    const int rem   = w_row - hpsel * ROWS_PER_HP;
    const int n     = rem / HROWS;                          // cutout
    const int il    = rem - n * HROWS;
    const int hp    = k + (hpsel << 3);                     // half-plane 0..23
    const int pi    = hp >> 1;                              // plane = b*C+c
    const int i     = (hp & 1) * HROWS + il;                // output row

    const int   sz    = sizes[n];
    const float scale = (float)sz * (1.0f / (float)S);

    // vertical interp (frac BEFORE clamp, matching reference)
    const float sy  = fmaxf(scale * ((float)i + 0.5f) - 0.5f, 0.0f);
    const float fiy = floorf(sy);
    const float fy  = sy - fiy;
    const int   iy0 = min((int)fiy, sz - 1);
    const int   iy1 = min(iy0 + 1, sz - 1);

    const float* plane = x + (size_t)pi * (H * W);
    const float* r0 = plane + (size_t)(offy[n] + iy0) * W;
    const float* r1 = plane + (size_t)(offy[n] + iy1) * W;

    // stage both full source rows (2 KB each): 4x coalesced 16B-per-lane DMA
    load_lds16(r0 + lane * 4,       &lds[wv][0][0]);
    load_lds16(r0 + 256 + lane * 4, &lds[wv][0][256]);
    load_lds16(r1 + lane * 4,       &lds[wv][1][0]);
    load_lds16(r1 + 256 + lane * 4, &lds[wv][1][256]);

    asm volatile("s_waitcnt vmcnt(0)" ::: "memory");
    __syncthreads();

    const int ox = offx[n];
    const float* l0 = &lds[wv][0][0];
    const float* l1 = &lds[wv][1][0];
    float* orow = out + (size_t)(n * PLANES + pi) * (S * S) + (size_t)i * S;

    #pragma unroll
    for (int r = 0; r < 4; ++r) {
        const int px = r * 64 + lane;                // lane-contiguous pixels
        if (r < 3 || px < S) {                       // 224 = 3*64 + 32
            const float sx  = fmaxf(scale * ((float)px + 0.5f) - 0.5f, 0.0f);
            const float fix = floorf(sx);
            const float fx  = sx - fix;
            const int   ix  = min((int)fix, sz - 1) + ox;

            // unclamped ix+1: only reachable with fx ~ 0 (weight ~1e-5), stays in LDS
            const float v00 = l0[ix], v01 = l0[ix + 1];
            const float v10 = l1[ix], v11 = l1[ix + 1];

            const float top = v00 + (v01 - v00) * fx;
            const float bot = v10 + (v11 - v10) * fx;
            orow[px] = top + (bot - top) * fy;
        }
    }
}

extern "C" void kernel_launch(void* const* d_in, const int* in_sizes, int n_in,
                              void* d_out, int out_size, void* d_ws, size_t ws_size,
                              hipStream_t stream) {
    const float* x     = (const float*)d_in[0];
    const int*   sizes = (const int*)d_in[1];
    const int*   offx  = (const int*)d_in[2];
    const int*   offy  = (const int*)d_in[3];
    float* out = (float*)d_out;

    cutouts_kernel<<<GRID, 256, 0, stream>>>(x, sizes, offx, offy, out);
}

// Round 4
// 45.262 us; speedup vs baseline: 2.7152x; 1.0493x over previous
//
#include <hip/hip_runtime.h>

// Problem constants: IMG=512, CUT_SIZE=224, CUTN=64, B=4, C=3
constexpr int S  = 224;
constexpr int B  = 4;
constexpr int C  = 3;
constexpr int H  = 512;
constexpr int W  = 512;
constexpr int N  = 64;
constexpr int PLANES = B * C;                    // 12
constexpr int HROWS  = S / 2;                    // 112 rows per half-plane
constexpr int PAIRS_PER_HP  = N * (HROWS / 2);   // 3584 row-pairs per half-plane
constexpr int PAIRS_PER_XCD = 3 * PAIRS_PER_HP;  // 10752 (24 half-planes / 8 XCDs)
constexpr int WPB    = 4;                        // waves per block, 1 row-PAIR each
constexpr int BLOCKS_PER_XCD = PAIRS_PER_XCD / WPB;  // 2688 (exact)
constexpr int GRID   = 8 * BLOCKS_PER_XCD;           // 21504

__device__ __forceinline__ void load_lds16(const float* g, float* l) {
    __builtin_amdgcn_global_load_lds(
        (const __attribute__((address_space(1))) void*)g,
        (__attribute__((address_space(3))) void*)l,
        16, 0, 0);
}

// stage one source row pair (iy0,iy1) for output row i into buf[2][W]
__device__ __forceinline__ void stage_row(const float* plane, int oy, int i,
                                          float scale, int sz, int lane,
                                          float* buf, float& fy_out) {
    const float sy  = fmaxf(scale * ((float)i + 0.5f) - 0.5f, 0.0f);
    const float fiy = floorf(sy);
    fy_out = sy - fiy;
    const int iy0 = min((int)fiy, sz - 1);
    const int iy1 = min(iy0 + 1, sz - 1);
    const float* r0 = plane + (size_t)(oy + iy0) * W;
    const float* r1 = plane + (size_t)(oy + iy1) * W;
    load_lds16(r0 + lane * 4,       buf);
    load_lds16(r0 + 256 + lane * 4, buf + 256);
    load_lds16(r1 + lane * 4,       buf + W);
    load_lds16(r1 + 256 + lane * 4, buf + W + 256);
}

__device__ __forceinline__ void compute_row(const float* buf, float fy, float scale,
                                            int sz, int ox, int lane, float* orow) {
    const float* l0 = buf;
    const float* l1 = buf + W;
    #pragma unroll
    for (int r = 0; r < 4; ++r) {
        const int px = r * 64 + lane;                // 224 = 3*64 + 32
        if (r < 3 || px < S) {
            const float sx  = fmaxf(scale * ((float)px + 0.5f) - 0.5f, 0.0f);
            const float fix = floorf(sx);
            const float fx  = sx - fix;
            const int   ix  = min((int)fix, sz - 1) + ox;
            // ix+1 can reach 512 only when fx==0.0 exactly (sz==224) -> weight-0 read
            const float v00 = l0[ix], v01 = l0[ix + 1];
            const float v10 = l1[ix], v11 = l1[ix + 1];
            const float top = v00 + (v01 - v00) * fx;
            const float bot = v10 + (v11 - v10) * fx;
            orow[px] = top + (bot - top) * fy;
        }
    }
}

__global__ __launch_bounds__(256) void cutouts_kernel(
    const float* __restrict__ x,
    const int*   __restrict__ sizes,
    const int*   __restrict__ offx,
    const int*   __restrict__ offy,
    float*       __restrict__ out)
{
    __shared__ float lds[WPB][2][2 * W];             // 32 KiB: per-wave double buffer

    const int lane = threadIdx.x & 63;
    const int wv   = threadIdx.x >> 6;

    // XCD-affine decomposition (half-plane ownership as R1/R2), one row-PAIR per wave
    const int k     = blockIdx.x & 7;                        // XCD (round-robin heuristic)
    const int pair  = (blockIdx.x >> 3) * WPB + wv;          // [0, PAIRS_PER_XCD)
    const int hpsel = pair / PAIRS_PER_HP;                   // 0..2
    const int rem   = pair - hpsel * PAIRS_PER_HP;
    const int n     = rem / (HROWS / 2);                     // cutout
    const int mp    = rem - n * (HROWS / 2);                 // pair-in-half
    const int hp    = k + (hpsel << 3);                      // half-plane 0..23
    const int pi    = hp >> 1;                               // plane = b*C+c
    const int i0    = (hp & 1) * HROWS + 2 * mp;             // first output row
    const int i1    = i0 + 1;

    const int   sz    = sizes[n];
    const float scale = (float)sz * (1.0f / (float)S);
    const int   oy    = offy[n];
    const int   ox    = offx[n];
    const float* plane = x + (size_t)pi * (H * W);

    float fy0, fy1;
    stage_row(plane, oy, i0, scale, sz, lane, &lds[wv][0][0], fy0);   // 4 DMAs
    stage_row(plane, oy, i1, scale, sz, lane, &lds[wv][1][0], fy1);   // 4 DMAs

    float* obase = out + (size_t)(n * PLANES + pi) * (S * S);

    asm volatile("s_waitcnt vmcnt(4)" ::: "memory");   // job0's 4 loads done
    __builtin_amdgcn_sched_barrier(0);
    compute_row(&lds[wv][0][0], fy0, scale, sz, ox, lane, obase + (size_t)i0 * S);

    // outstanding: job1's 4 loads (oldest) + row0's stores; in-order retirement
    asm volatile("s_waitcnt vmcnt(4)" ::: "memory");   // job1's loads done
    __builtin_amdgcn_sched_barrier(0);
    compute_row(&lds[wv][1][0], fy1, scale, sz, ox, lane, obase + (size_t)i1 * S);
}

extern "C" void kernel_launch(void* const* d_in, const int* in_sizes, int n_in,
                              void* d_out, int out_size, void* d_ws, size_t ws_size,
                              hipStream_t stream) {
    const float* x     = (const float*)d_in[0];
    const int*   sizes = (const int*)d_in[1];
    const int*   offx  = (const int*)d_in[2];
    const int*   offy  = (const int*)d_in[3];
    float* out = (float*)d_out;

    cutouts_kernel<<<GRID, 256, 0, stream>>>(x, sizes, offx, offy, out);
}